// Round 10
// baseline (337.933 us; speedup 1.0000x reference)
//
#include <hip/hip_runtime.h>
#include <hip/hip_bf16.h>
#include <math.h>

#define LP 1000
#define NCMP 64
#define NSPLIT 3

__device__ __forceinline__ float rcp_fast(float x) { return __builtin_amdgcn_rcpf(x); }

// ---------------- GEMM body: Y[M,128] = op(X)[M,K] @ W[K,128] + b ----------------
// 32-row tile, 256 threads, thread = 4x4, X transposed in LDS, software-pipelined.
template<bool RELU_IN, bool NO_BIAS>
__device__ __forceinline__ void gemm_body(const float* X, const float* W, const float* __restrict__ bias,
                                          float* Y, int K, int rowbase)
{
    __shared__ __align__(16) float Ws[32][128];
    __shared__ __align__(16) float Xt[32][36];
    const int t  = threadIdx.x;
    const int r0 = (t >> 5) * 4;
    const int c0 = (t & 31) * 4;
    const int xr = t >> 3, xk = (t & 7) << 2;
    const int xrow = rowbase + xr;
    float4 xv = *(const float4*)(X + (long)xrow * K + xk);
    float4 wv[4];
    #pragma unroll
    for (int u = 0; u < 4; ++u) {
        int s = t + u * 256, r = s >> 5, cb = (s & 31) << 2;
        wv[u] = *(const float4*)(W + (long)r * 128 + cb);
    }
    float acc[4][4] = {};
    for (int k0 = 0; k0 < K; k0 += 32) {
        float4 xs = xv;
        if (RELU_IN) { xs.x = fmaxf(xs.x,0.f); xs.y = fmaxf(xs.y,0.f);
                       xs.z = fmaxf(xs.z,0.f); xs.w = fmaxf(xs.w,0.f); }
        Xt[xk+0][xr] = xs.x; Xt[xk+1][xr] = xs.y; Xt[xk+2][xr] = xs.z; Xt[xk+3][xr] = xs.w;
        #pragma unroll
        for (int u = 0; u < 4; ++u) {
            int s = t + u * 256, r = s >> 5, cb = (s & 31) << 2;
            *(float4*)&Ws[r][cb] = wv[u];
        }
        __syncthreads();
        if (k0 + 32 < K) {
            xv = *(const float4*)(X + (long)xrow * K + k0 + 32 + xk);
            #pragma unroll
            for (int u = 0; u < 4; ++u) {
                int s = t + u * 256, r = s >> 5, cb = (s & 31) << 2;
                wv[u] = *(const float4*)(W + (long)(k0 + 32 + r) * 128 + cb);
            }
        }
        #pragma unroll
        for (int kk = 0; kk < 32; ++kk) {
            float4 w4 = *(const float4*)&Ws[kk][c0];
            float4 x4 = *(const float4*)&Xt[kk][r0];
            acc[0][0] = fmaf(x4.x, w4.x, acc[0][0]); acc[0][1] = fmaf(x4.x, w4.y, acc[0][1]);
            acc[0][2] = fmaf(x4.x, w4.z, acc[0][2]); acc[0][3] = fmaf(x4.x, w4.w, acc[0][3]);
            acc[1][0] = fmaf(x4.y, w4.x, acc[1][0]); acc[1][1] = fmaf(x4.y, w4.y, acc[1][1]);
            acc[1][2] = fmaf(x4.y, w4.z, acc[1][2]); acc[1][3] = fmaf(x4.y, w4.w, acc[1][3]);
            acc[2][0] = fmaf(x4.z, w4.x, acc[2][0]); acc[2][1] = fmaf(x4.z, w4.y, acc[2][1]);
            acc[2][2] = fmaf(x4.z, w4.z, acc[2][2]); acc[2][3] = fmaf(x4.z, w4.w, acc[2][3]);
            acc[3][0] = fmaf(x4.w, w4.x, acc[3][0]); acc[3][1] = fmaf(x4.w, w4.y, acc[3][1]);
            acc[3][2] = fmaf(x4.w, w4.z, acc[3][2]); acc[3][3] = fmaf(x4.w, w4.w, acc[3][3]);
        }
        __syncthreads();
    }
    float4 bv = NO_BIAS ? make_float4(0.f,0.f,0.f,0.f) : *(const float4*)(bias + c0);
    #pragma unroll
    for (int i = 0; i < 4; ++i) {
        int row = rowbase + r0 + i;
        float4 o;
        o.x = acc[i][0] + bv.x; o.y = acc[i][1] + bv.y;
        o.z = acc[i][2] + bv.z; o.w = acc[i][3] + bv.w;
        *(float4*)(Y + (long)row * 128 + c0) = o;
    }
}

// ---- pre0: 0-9: Wp=emb_w@wq_w; 10: bp=emb_b@wq_w+wq_b + zero Asum/cpe;
//            11-14: Wvo=wv_w@wo_w; 15: bvo=wv_b@wo_w+wo_b ----
__global__ __launch_bounds__(256) void pre0_k(const float* __restrict__ emb_w, const float* __restrict__ emb_b,
                                              const float* __restrict__ wq_w, const float* __restrict__ wq_b,
                                              const float* __restrict__ wv_w, const float* __restrict__ wv_b,
                                              const float* __restrict__ wo_w, const float* __restrict__ wo_b,
                                              float* __restrict__ Wp, float* __restrict__ bp,
                                              float* __restrict__ Wvo, float* __restrict__ bvo,
                                              float* __restrict__ zbase)   // Asum(8)+cpe(1024) contiguous
{
    const int bid = blockIdx.x;
    if (bid < 10) { gemm_body<false,true>(emb_w, wq_w, nullptr, Wp, 128, bid * 32); return; }
    if (bid >= 11 && bid < 15) { gemm_body<false,true>(wv_w, wo_w, nullptr, Wvo, 128, (bid - 11) * 32); return; }
    int t = threadIdx.x;
    if (bid == 10 && t >= 128) {      // zero Asum + cpe (1032 floats)
        for (int i = t - 128; i < 1032; i += 128) zbase[i] = 0.f;
        return;
    }
    if (t < 128) {
        const float* vb = (bid == 10) ? emb_b : wv_b;
        const float* Wm = (bid == 10) ? wq_w  : wo_w;
        const float* ab = (bid == 10) ? wq_b  : wo_b;
        float a0 = 0.f, a1 = 0.f, a2 = 0.f, a3 = 0.f;
        for (int k = 0; k < 128; k += 4) {
            a0 = fmaf(vb[k+0], Wm[(k+0)*128 + t], a0);
            a1 = fmaf(vb[k+1], Wm[(k+1)*128 + t], a1);
            a2 = fmaf(vb[k+2], Wm[(k+2)*128 + t], a2);
            a3 = fmaf(vb[k+3], Wm[(k+3)*128 + t], a3);
        }
        float* dst = (bid == 10) ? bp : bvo;
        dst[t] = (a0 + a1) + (a2 + a3) + ab[t];
    }
}

// ---- qkv: 0-249 Q=PE@Wp+bp (K=320); 250-499 K=PFX@wk+bk; 500-515 Cj=relu(CF)@jc+bc ----
__global__ __launch_bounds__(256) void qkv_k(const float* __restrict__ PE, const float* __restrict__ Wp,
                                             const float* __restrict__ bp, const float* __restrict__ PFX,
                                             const float* __restrict__ wk_w, const float* __restrict__ wk_b,
                                             const float* __restrict__ CF, const float* __restrict__ jc_w,
                                             const float* __restrict__ jc_b,
                                             float* __restrict__ Qo, float* __restrict__ Ko, float* __restrict__ Cj)
{
    if (blockIdx.x < 250)
        gemm_body<false,false>(PE, Wp, bp, Qo, 320, blockIdx.x * 32);
    else if (blockIdx.x < 500)
        gemm_body<false,false>(PFX, wk_w, wk_b, Ko, 128, (blockIdx.x - 250) * 32);
    else
        gemm_body<true,false>(CF, jc_w, jc_b, Cj, 128, (blockIdx.x - 500) * 32);
}

// ---------------- flash attention v6: TQ=48, TK=64, sp=3 splits, 256 threads (unchanged) ----------
__global__ __launch_bounds__(256) void flash6_k(const float* __restrict__ Q, const float* __restrict__ Kg,
                                                const float* __restrict__ Vg, float* __restrict__ Opart,
                                                float* __restrict__ mpart, float* __restrict__ lpart)
{
    __shared__ __align__(16) float Qs[48][132];
    __shared__ __align__(16) float KVs[64][132];
    __shared__ __align__(16) float Ps[48][68];
    const int t  = threadIdx.x;
    const int tr = t >> 4;
    const int tc = t & 15;
    const int qt = blockIdx.x, sp = blockIdx.y, b = blockIdx.z;
    const int q0 = qt * 48;
    const int kt0 = (sp * 16) / NSPLIT;
    const int kt1 = ((sp + 1) * 16) / NSPLIT;
    const float SCALE = 0.08838834764831845f;
    const float L2E   = 1.4426950408889634f;

    #pragma unroll
    for (int u = 0; u < 6; ++u) {
        int s = t + u * 256, r = s >> 5, cb = (s & 31) << 2;
        float4 v = make_float4(0.f, 0.f, 0.f, 0.f);
        if (q0 + r < LP) v = *(const float4*)(Q + ((long)b * LP + q0 + r) * 128 + cb);
        *(float4*)&Qs[r][cb] = v;
    }
    float m_i[3] = { -3.0e38f, -3.0e38f, -3.0e38f };
    float l_i[3] = { 0.f, 0.f, 0.f };
    float Oa[3][8] = {};

    for (int kt = kt0; kt < kt1; ++kt) {
        const int key0 = kt * 64;
        __syncthreads();
        #pragma unroll
        for (int u = 0; u < 8; ++u) {
            int s = t + u * 256, r = s >> 5, cb = (s & 31) << 2;
            float4 v = make_float4(0.f, 0.f, 0.f, 0.f);
            if (key0 + r < LP) v = *(const float4*)(Kg + ((long)b * LP + key0 + r) * 128 + cb);
            *(float4*)&KVs[r][cb] = v;
        }
        __syncthreads();
        float sacc[3][4] = {};
        #pragma unroll 4
        for (int d4 = 0; d4 < 32; ++d4) {
            float4 q0v = *(const float4*)&Qs[3 * tr + 0][d4 << 2];
            float4 q1v = *(const float4*)&Qs[3 * tr + 1][d4 << 2];
            float4 q2v = *(const float4*)&Qs[3 * tr + 2][d4 << 2];
            #pragma unroll
            for (int j = 0; j < 4; ++j) {
                float4 kv = *(const float4*)&KVs[tc + (j << 4)][d4 << 2];
                sacc[0][j] += q0v.x*kv.x + q0v.y*kv.y + q0v.z*kv.z + q0v.w*kv.w;
                sacc[1][j] += q1v.x*kv.x + q1v.y*kv.y + q1v.z*kv.z + q1v.w*kv.w;
                sacc[2][j] += q2v.x*kv.x + q2v.y*kv.y + q2v.z*kv.z + q2v.w*kv.w;
            }
        }
        __syncthreads();
        float4 vreg[8];
        #pragma unroll
        for (int u = 0; u < 8; ++u) {
            int s = t + u * 256, r = s >> 5, cb = (s & 31) << 2;
            vreg[u] = make_float4(0.f, 0.f, 0.f, 0.f);
            if (key0 + r < LP) vreg[u] = *(const float4*)(Vg + ((long)b * LP + key0 + r) * 128 + cb);
        }
        #pragma unroll
        for (int j = 0; j < 4; ++j) {
            bool valid = (key0 + tc + (j << 4)) < LP;
            #pragma unroll
            for (int i = 0; i < 3; ++i) {
                float sv = sacc[i][j] * SCALE;
                sacc[i][j] = valid ? sv : -3.0e38f;
            }
        }
        #pragma unroll
        for (int i = 0; i < 3; ++i) {
            float tm = fmaxf(fmaxf(sacc[i][0], sacc[i][1]), fmaxf(sacc[i][2], sacc[i][3]));
            tm = fmaxf(tm, __shfl_xor(tm, 1));
            tm = fmaxf(tm, __shfl_xor(tm, 2));
            tm = fmaxf(tm, __shfl_xor(tm, 4));
            tm = fmaxf(tm, __shfl_xor(tm, 8));
            float mnew  = fmaxf(m_i[i], tm);
            float alpha = exp2f((m_i[i] - mnew) * L2E);
            float ps = 0.f;
            #pragma unroll
            for (int j = 0; j < 4; ++j) {
                float p = exp2f((sacc[i][j] - mnew) * L2E);
                Ps[3 * tr + i][tc + (j << 4)] = p;
                ps += p;
            }
            ps += __shfl_xor(ps, 1);
            ps += __shfl_xor(ps, 2);
            ps += __shfl_xor(ps, 4);
            ps += __shfl_xor(ps, 8);
            l_i[i] = l_i[i] * alpha + ps;
            m_i[i] = mnew;
            #pragma unroll
            for (int j = 0; j < 8; ++j) Oa[i][j] *= alpha;
        }
        #pragma unroll
        for (int u = 0; u < 8; ++u) {
            int s = t + u * 256, r = s >> 5, cb = (s & 31) << 2;
            *(float4*)&KVs[r][cb] = vreg[u];
        }
        __syncthreads();
        #pragma unroll 2
        for (int cg = 0; cg < 16; ++cg) {
            float4 pa = *(const float4*)&Ps[3 * tr + 0][cg << 2];
            float4 pb = *(const float4*)&Ps[3 * tr + 1][cg << 2];
            float4 pc = *(const float4*)&Ps[3 * tr + 2][cg << 2];
            #pragma unroll
            for (int e = 0; e < 4; ++e) {
                int c = (cg << 2) + e;
                float4 va = *(const float4*)&KVs[c][tc << 2];
                float4 vb = *(const float4*)&KVs[c][64 + (tc << 2)];
                float p0 = (e == 0) ? pa.x : (e == 1) ? pa.y : (e == 2) ? pa.z : pa.w;
                float p1 = (e == 0) ? pb.x : (e == 1) ? pb.y : (e == 2) ? pb.z : pb.w;
                float p2 = (e == 0) ? pc.x : (e == 1) ? pc.y : (e == 2) ? pc.z : pc.w;
                Oa[0][0] = fmaf(p0, va.x, Oa[0][0]); Oa[0][1] = fmaf(p0, va.y, Oa[0][1]);
                Oa[0][2] = fmaf(p0, va.z, Oa[0][2]); Oa[0][3] = fmaf(p0, va.w, Oa[0][3]);
                Oa[0][4] = fmaf(p0, vb.x, Oa[0][4]); Oa[0][5] = fmaf(p0, vb.y, Oa[0][5]);
                Oa[0][6] = fmaf(p0, vb.z, Oa[0][6]); Oa[0][7] = fmaf(p0, vb.w, Oa[0][7]);
                Oa[1][0] = fmaf(p1, va.x, Oa[1][0]); Oa[1][1] = fmaf(p1, va.y, Oa[1][1]);
                Oa[1][2] = fmaf(p1, va.z, Oa[1][2]); Oa[1][3] = fmaf(p1, va.w, Oa[1][3]);
                Oa[1][4] = fmaf(p1, vb.x, Oa[1][4]); Oa[1][5] = fmaf(p1, vb.y, Oa[1][5]);
                Oa[1][6] = fmaf(p1, vb.z, Oa[1][6]); Oa[1][7] = fmaf(p1, vb.w, Oa[1][7]);
                Oa[2][0] = fmaf(p2, va.x, Oa[2][0]); Oa[2][1] = fmaf(p2, va.y, Oa[2][1]);
                Oa[2][2] = fmaf(p2, va.z, Oa[2][2]); Oa[2][3] = fmaf(p2, va.w, Oa[2][3]);
                Oa[2][4] = fmaf(p2, vb.x, Oa[2][4]); Oa[2][5] = fmaf(p2, vb.y, Oa[2][5]);
                Oa[2][6] = fmaf(p2, vb.z, Oa[2][6]); Oa[2][7] = fmaf(p2, vb.w, Oa[2][7]);
            }
        }
    }
    #pragma unroll
    for (int i = 0; i < 3; ++i) {
        int row = q0 + 3 * tr + i;
        if (row < LP) {
            long base = ((long)sp * 1024000) + ((long)b * LP + row) * 128;
            *(float4*)(Opart + base + (tc << 2))      = make_float4(Oa[i][0], Oa[i][1], Oa[i][2], Oa[i][3]);
            *(float4*)(Opart + base + 64 + (tc << 2)) = make_float4(Oa[i][4], Oa[i][5], Oa[i][6], Oa[i][7]);
            if (tc == 0) {
                mpart[(long)sp * 8000 + b * LP + row] = m_i[i];
                lpart[(long)sp * 8000 + b * LP + row] = l_i[i];
            }
        }
    }
}

// ---------------- megatail: per 16-row tile, wo+jp+sigA+tanh-reduce fused ----------------
// grid (63, 8), 256 threads, ~70 KB LDS -> 2 blocks/CU. Phase D reads via AshT transpose
// (b128) + reg-cached AttS; GEMM2 X reads as b128 quads.
__global__ __launch_bounds__(256) void megatail_k(
    const float* __restrict__ Opart, const float* __restrict__ mp, const float* __restrict__ lp,
    const float* __restrict__ Wvo, const float* __restrict__ bvo,
    const float* __restrict__ jp_w, const float* __restrict__ jp_b,
    const float* __restrict__ Cj, const float* __restrict__ CF,
    float* __restrict__ Asum, float* __restrict__ cpe)
{
    __shared__ __align__(16) float WsA[32][132];   // GEMM W-tiles; rows 0-15 reused as Psh after
    __shared__ __align__(16) float Xt[32][20];
    __shared__ __align__(16) float AttS[16][132];
    __shared__ __align__(16) float Csh[64][132];
    __shared__ __align__(16) float Ash[16][64];
    __shared__ __align__(16) float AshT[64][20];   // transpose for phase D b128 reads
    __shared__ float red[256];
    const int t = threadIdx.x;
    const int p0 = blockIdx.x * 16;
    const int b  = blockIdx.y;
    const float L2E = 1.4426950408889634f;

    #pragma unroll
    for (int u = 0; u < 8; ++u) {
        int s = t + u * 256, r = s >> 5, cb = (s & 31) << 2;
        *(float4*)&Csh[r][cb] = *(const float4*)(Cj + ((long)b * NCMP + r) * 128 + cb);
    }

    // ---- GEMM1: Att = mergeN(Opart) @ Wvo + bvo ----
    const int r0 = (t >> 5) * 2, c0 = (t & 31) * 4;
    const int xr = t >> 3, xk = (t & 7) << 2;
    int prow = p0 + xr; if (prow > LP - 1) prow = LP - 1;
    const long g = (long)b * LP + prow;
    float wgt[NSPLIT]; float linv = 0.f;
    if (t < 128) {
        float mm = -3.0e38f;
        #pragma unroll
        for (int s = 0; s < NSPLIT; ++s) mm = fmaxf(mm, mp[g + (long)s * 8000]);
        float ls = 0.f;
        #pragma unroll
        for (int s = 0; s < NSPLIT; ++s) {
            wgt[s] = exp2f((mp[g + (long)s * 8000] - mm) * L2E);
            ls += wgt[s] * lp[g + (long)s * 8000];
        }
        linv = 1.0f / ls;
    }
    float4 xv = make_float4(0.f,0.f,0.f,0.f);
    float4 wv[4];
    if (t < 128) {
        float4 a = make_float4(0.f,0.f,0.f,0.f);
        #pragma unroll
        for (int s = 0; s < NSPLIT; ++s) {
            float4 p = *(const float4*)(Opart + (long)s * 1024000 + g * 128 + xk);
            a.x = fmaf(wgt[s], p.x, a.x); a.y = fmaf(wgt[s], p.y, a.y);
            a.z = fmaf(wgt[s], p.z, a.z); a.w = fmaf(wgt[s], p.w, a.w);
        }
        xv = make_float4(a.x * linv, a.y * linv, a.z * linv, a.w * linv);
    }
    #pragma unroll
    for (int u = 0; u < 4; ++u) {
        int s = t + u * 256, r = s >> 5, cb = (s & 31) << 2;
        wv[u] = *(const float4*)(Wvo + (long)r * 128 + cb);
    }
    float acc[2][4] = {};
    for (int k0 = 0; k0 < 128; k0 += 32) {
        if (t < 128) { Xt[xk+0][xr]=xv.x; Xt[xk+1][xr]=xv.y; Xt[xk+2][xr]=xv.z; Xt[xk+3][xr]=xv.w; }
        #pragma unroll
        for (int u = 0; u < 4; ++u) {
            int s = t + u * 256, r = s >> 5, cb = (s & 31) << 2;
            *(float4*)&WsA[r][cb] = wv[u];
        }
        __syncthreads();
        if (k0 + 32 < 128) {
            int kn = k0 + 32;
            if (t < 128) {
                float4 a = make_float4(0.f,0.f,0.f,0.f);
                #pragma unroll
                for (int s = 0; s < NSPLIT; ++s) {
                    float4 p = *(const float4*)(Opart + (long)s * 1024000 + g * 128 + kn + xk);
                    a.x = fmaf(wgt[s], p.x, a.x); a.y = fmaf(wgt[s], p.y, a.y);
                    a.z = fmaf(wgt[s], p.z, a.z); a.w = fmaf(wgt[s], p.w, a.w);
                }
                xv = make_float4(a.x * linv, a.y * linv, a.z * linv, a.w * linv);
            }
            #pragma unroll
            for (int u = 0; u < 4; ++u) {
                int s = t + u * 256, r = s >> 5, cb = (s & 31) << 2;
                wv[u] = *(const float4*)(Wvo + (long)(kn + r) * 128 + cb);
            }
        }
        #pragma unroll
        for (int kk = 0; kk < 32; ++kk) {
            float2 x2 = *(const float2*)&Xt[kk][r0];
            float4 w4 = *(const float4*)&WsA[kk][c0];
            acc[0][0]=fmaf(x2.x,w4.x,acc[0][0]); acc[0][1]=fmaf(x2.x,w4.y,acc[0][1]);
            acc[0][2]=fmaf(x2.x,w4.z,acc[0][2]); acc[0][3]=fmaf(x2.x,w4.w,acc[0][3]);
            acc[1][0]=fmaf(x2.y,w4.x,acc[1][0]); acc[1][1]=fmaf(x2.y,w4.y,acc[1][1]);
            acc[1][2]=fmaf(x2.y,w4.z,acc[1][2]); acc[1][3]=fmaf(x2.y,w4.w,acc[1][3]);
        }
        __syncthreads();
    }
    {   // Att -> AttS (protein_feats, pre-relu)
        float4 bv1 = *(const float4*)(bvo + c0);
        #pragma unroll
        for (int i = 0; i < 2; ++i)
            *(float4*)&AttS[r0 + i][c0] =
                make_float4(acc[i][0]+bv1.x, acc[i][1]+bv1.y, acc[i][2]+bv1.z, acc[i][3]+bv1.w);
    }
    // ---- GEMM2: P = relu(Att) @ jp_w + jp_b  (X from AttS, b128 quads + on-the-fly relu) ----
    float4 wv2[4];
    #pragma unroll
    for (int u = 0; u < 4; ++u) {
        int s = t + u * 256, r = s >> 5, cb = (s & 31) << 2;
        wv2[u] = *(const float4*)(jp_w + (long)r * 128 + cb);
    }
    float ac2[2][4] = {};
    for (int k0 = 0; k0 < 128; k0 += 32) {
        #pragma unroll
        for (int u = 0; u < 4; ++u) {
            int s = t + u * 256, r = s >> 5, cb = (s & 31) << 2;
            *(float4*)&WsA[r][cb] = wv2[u];
        }
        __syncthreads();        // also makes AttS visible on first iteration
        if (k0 + 32 < 128) {
            #pragma unroll
            for (int u = 0; u < 4; ++u) {
                int s = t + u * 256, r = s >> 5, cb = (s & 31) << 2;
                wv2[u] = *(const float4*)(jp_w + (long)(k0 + 32 + r) * 128 + cb);
            }
        }
        #pragma unroll
        for (int kq = 0; kq < 8; ++kq) {
            float4 xa = *(const float4*)&AttS[r0 + 0][k0 + (kq << 2)];
            float4 xb = *(const float4*)&AttS[r0 + 1][k0 + (kq << 2)];
            #pragma unroll
            for (int e = 0; e < 4; ++e) {
                float x0 = fmaxf((e==0)?xa.x:(e==1)?xa.y:(e==2)?xa.z:xa.w, 0.f);
                float x1 = fmaxf((e==0)?xb.x:(e==1)?xb.y:(e==2)?xb.z:xb.w, 0.f);
                float4 w4 = *(const float4*)&WsA[(kq << 2) + e][c0];
                ac2[0][0]=fmaf(x0,w4.x,ac2[0][0]); ac2[0][1]=fmaf(x0,w4.y,ac2[0][1]);
                ac2[0][2]=fmaf(x0,w4.z,ac2[0][2]); ac2[0][3]=fmaf(x0,w4.w,ac2[0][3]);
                ac2[1][0]=fmaf(x1,w4.x,ac2[1][0]); ac2[1][1]=fmaf(x1,w4.y,ac2[1][1]);
                ac2[1][2]=fmaf(x1,w4.z,ac2[1][2]); ac2[1][3]=fmaf(x1,w4.w,ac2[1][3]);
            }
        }
        __syncthreads();
    }
    float (*Psh)[132] = WsA;                      // WsA dead -> rows 0-15 hold P
    {
        float4 b2 = *(const float4*)(jp_b + c0);
        #pragma unroll
        for (int i = 0; i < 2; ++i)
            *(float4*)&Psh[r0 + i][c0] =
                make_float4(ac2[i][0]+b2.x, ac2[i][1]+b2.y, ac2[i][2]+b2.z, ac2[i][3]+b2.w);
    }
    __syncthreads();
    // ---- phase C: A = sigmoid(P Cj^T) -> Ash + AshT + Asum ----
    const int tr = t >> 4, tc = t & 15;
    float sacc[4] = {};
    #pragma unroll 4
    for (int d4 = 0; d4 < 32; ++d4) {
        float4 p4 = *(const float4*)&Psh[tr][d4 << 2];
        #pragma unroll
        for (int j = 0; j < 4; ++j) {
            float4 cv = *(const float4*)&Csh[tc + (j << 4)][d4 << 2];
            sacc[j] += p4.x*cv.x + p4.y*cv.y + p4.z*cv.z + p4.w*cv.w;
        }
    }
    float lsum = 0.f;
    {
        int gi = p0 + tr;
        #pragma unroll
        for (int j = 0; j < 4; ++j) {
            float sg = rcp_fast(1.f + exp2f(-sacc[j] * L2E));
            if (gi < LP) {
                Ash[tr][tc + (j << 4)]  = sg;
                AshT[tc + (j << 4)][tr] = sg;
                lsum += sg;
            }
        }
    }
    red[t] = lsum;
    __syncthreads();
    for (int off = 128; off > 0; off >>= 1) {
        if (t < off) red[t] += red[t + off];
        __syncthreads();
    }
    if (t == 0) atomicAdd(Asum + b, red[0]);
    __syncthreads();
    // Csh <- raw CF
    #pragma unroll
    for (int u = 0; u < 8; ++u) {
        int s = t + u * 256, r = s >> 5, cb = (s & 31) << 2;
        *(float4*)&Csh[r][cb] = *(const float4*)(CF + ((long)b * NCMP + r) * 128 + cb);
    }
    __syncthreads();
    // ---- phase D: cpe += sum_{i,k} tanh(AttS[i][d]*CF[k][d]) * A[i][k] ----
    const float TWO_L2E = 2.8853900817779268f;    // 2*log2(e)
    const int d  = t & 127;
    const int kh = t >> 7;
    const int iiN = (LP - p0 < 16) ? (LP - p0) : 16;   // 16 or 8 (multiple of 4)
    float areg[16];
    #pragma unroll
    for (int ii = 0; ii < 16; ++ii) areg[ii] = AttS[ii][d] * TWO_L2E;
    float accD = 0.f;
    for (int kk = 0; kk < 32; ++kk) {
        const int k = (kh << 5) + kk;
        const float cv = Csh[k][d];               // broadcast within d-groups
        for (int iq = 0; iq < iiN; iq += 4) {
            float4 a4 = *(const float4*)&AshT[k][iq];
            float e0 = exp2f(areg[iq+0] * cv);
            float e1 = exp2f(areg[iq+1] * cv);
            float e2 = exp2f(areg[iq+2] * cv);
            float e3 = exp2f(areg[iq+3] * cv);
            accD = fmaf(1.f - 2.f * rcp_fast(e0 + 1.f), a4.x, accD);
            accD = fmaf(1.f - 2.f * rcp_fast(e1 + 1.f), a4.y, accD);
            accD = fmaf(1.f - 2.f * rcp_fast(e2 + 1.f), a4.z, accD);
            accD = fmaf(1.f - 2.f * rcp_fast(e3 + 1.f), a4.w, accD);
        }
    }
    red[t] = accD;
    __syncthreads();
    if (t < 128) atomicAdd(cpe + (long)b * 128 + t, red[t] + red[t + 128]);
}

// ---------------- c12: fused c1 (h1 slice recompute) + c2 split-K partials, 128 blocks ----------
__global__ __launch_bounds__(256) void c12_k(const float* __restrict__ cpe, const float* __restrict__ Asum,
                                             const float* __restrict__ c1_w, const float* __restrict__ c1_b,
                                             const float* __restrict__ c2_w, float* __restrict__ part)
{
    __shared__ float sc[8][128];
    __shared__ float ins[8][8];
    const int t = threadIdx.x, ks = blockIdx.x, k0 = ks * 8;
    #pragma unroll
    for (int u = 0; u < 4; ++u) {
        int idx = t + u * 256;
        sc[idx >> 7][idx & 127] = cpe[idx] * rcp_fast(Asum[idx >> 7]);
    }
    __syncthreads();
    if (t < 64) {   // h1[b][k0+kk] = relu(sc[b] . c1_w[:,k0+kk] + b1)
        int b = t >> 3, kk = t & 7;
        int n1 = k0 + kk;
        float a0 = 0.f, a1 = 0.f, a2 = 0.f, a3 = 0.f;
        #pragma unroll 8
        for (int j = 0; j < 128; j += 4) {
            a0 = fmaf(sc[b][j+0], c1_w[(long)(j+0)*1024 + n1], a0);
            a1 = fmaf(sc[b][j+1], c1_w[(long)(j+1)*1024 + n1], a1);
            a2 = fmaf(sc[b][j+2], c1_w[(long)(j+2)*1024 + n1], a2);
            a3 = fmaf(sc[b][j+3], c1_w[(long)(j+3)*1024 + n1], a3);
        }
        ins[b][kk] = fmaxf((a0 + a1) + (a2 + a3) + c1_b[n1], 0.f);
    }
    __syncthreads();
    const int n = (t & 63) * 4 + (t >> 6) * 256;
    float4 acc[8] = {};
    #pragma unroll
    for (int kk = 0; kk < 8; ++kk) {
        float4 w4 = *(const float4*)(c2_w + (long)(k0 + kk) * 1024 + n);
        #pragma unroll
        for (int b = 0; b < 8; ++b) {
            float s = ins[b][kk];
            acc[b].x = fmaf(s, w4.x, acc[b].x); acc[b].y = fmaf(s, w4.y, acc[b].y);
            acc[b].z = fmaf(s, w4.z, acc[b].z); acc[b].w = fmaf(s, w4.w, acc[b].w);
        }
    }
    #pragma unroll
    for (int b = 0; b < 8; ++b)
        *(float4*)(part + ((long)(ks * 8 + b)) * 1024 + n) = acc[b];
}

// ------- c3+c4 fused: h2=relu(sum part2 + b2); h3=relu(h2@c3_w+b3); out[b]=h3.c4_w+b4 -------
__global__ __launch_bounds__(256) void c3m_k(const float* __restrict__ part2, const float* __restrict__ c2_b,
                                             const float* __restrict__ c3_w, const float* __restrict__ c3_b,
                                             const float* __restrict__ c4_w, const float* __restrict__ c4_b,
                                             float* __restrict__ out)
{
    __shared__ float Hs[1024];
    __shared__ float red[256];
    const int t = threadIdx.x, b = blockIdx.x;
    float4 acc4 = make_float4(0.f,0.f,0.f,0.f);
    #pragma unroll 4
    for (int ks = 0; ks < 128; ++ks) {
        float4 p = *(const float4*)(part2 + ((long)(ks * 8 + b)) * 1024 + t * 4);
        acc4.x += p.x; acc4.y += p.y; acc4.z += p.z; acc4.w += p.w;
    }
    {
        float4 bb = *(const float4*)(c2_b + t * 4);
        Hs[t*4+0] = fmaxf(acc4.x + bb.x, 0.f);
        Hs[t*4+1] = fmaxf(acc4.y + bb.y, 0.f);
        Hs[t*4+2] = fmaxf(acc4.z + bb.z, 0.f);
        Hs[t*4+3] = fmaxf(acc4.w + bb.w, 0.f);
    }
    __syncthreads();
    float a0 = 0.f, a1 = 0.f, a2 = 0.f, a3 = 0.f;
    #pragma unroll 8
    for (int k = 0; k < 1024; k += 4) {
        a0 = fmaf(Hs[k+0], c3_w[(long)(k+0)*256 + t], a0);
        a1 = fmaf(Hs[k+1], c3_w[(long)(k+1)*256 + t], a1);
        a2 = fmaf(Hs[k+2], c3_w[(long)(k+2)*256 + t], a2);
        a3 = fmaf(Hs[k+3], c3_w[(long)(k+3)*256 + t], a3);
    }
    float h3v = fmaxf((a0 + a1) + (a2 + a3) + c3_b[t], 0.f);
    red[t] = h3v * c4_w[t];
    __syncthreads();
    for (int off = 128; off > 0; off >>= 1) {
        if (t < off) red[t] += red[t + off];
        __syncthreads();
    }
    if (t == 0) out[b] = red[0] + c4_b[0];
}

extern "C" void kernel_launch(void* const* d_in, const int* in_sizes, int n_in,
                              void* d_out, int out_size, void* d_ws, size_t ws_size,
                              hipStream_t stream)
{
    const float* PE   = (const float*)d_in[0];
    const float* PFX  = (const float*)d_in[1];
    const float* CF   = (const float*)d_in[2];
    const float* emb_w = (const float*)d_in[3];  const float* emb_b = (const float*)d_in[4];
    const float* wq_w  = (const float*)d_in[5];  const float* wq_b  = (const float*)d_in[6];
    const float* wk_w  = (const float*)d_in[7];  const float* wk_b  = (const float*)d_in[8];
    const float* wv_w  = (const float*)d_in[9];  const float* wv_b  = (const float*)d_in[10];
    const float* wo_w  = (const float*)d_in[11]; const float* wo_b  = (const float*)d_in[12];
    const float* jp_w  = (const float*)d_in[13]; const float* jp_b  = (const float*)d_in[14];
    const float* jc_w  = (const float*)d_in[15]; const float* jc_b  = (const float*)d_in[16];
    const float* c1_w  = (const float*)d_in[17]; const float* c1_b  = (const float*)d_in[18];
    const float* c2_w  = (const float*)d_in[19]; const float* c2_b  = (const float*)d_in[20];
    const float* c3_w  = (const float*)d_in[21]; const float* c3_b  = (const float*)d_in[22];
    const float* c4_w  = (const float*)d_in[23]; const float* c4_b  = (const float*)d_in[24];

    float* ws     = (float*)d_ws;
    float* bufQ   = ws;                    // 1,024,000 (Q; later c2-partials alias, spills into bufK)
    float* bufK   = bufQ   + 1024000;      // 1,024,000
    float* bufC   = bufK   + 1024000;      //    65,536 (jc output)
    float* Opart  = bufC   + 65536;        // 3,072,000 (3-way flash partials)
    float* mpart  = Opart  + 3072000;      //    24,000
    float* lpart  = mpart  + 24000;        //    24,000
    float* Asum   = lpart  + 24000;        //         8
    float* cpe    = Asum   + 8;            //     1,024 (contiguous after Asum — zeroed in pre0)
    float* bprime = cpe    + 1024;         //       128 (Q bias)
    float* bufWp  = bprime + 128;          //    40,960 (emb_w @ wq_w)
    float* bufWvo = bufWp  + 40960;        //    16,384 (wv_w @ wo_w)
    float* bufbvo = bufWvo + 16384;        //       128 (wv_b @ wo_w + wo_b)
    float* part2  = bufQ;                  // c2 partials: 128*8*1024 = 1,048,576 (bufQ+start of bufK, both dead)
    // total ~5.27M floats = ~21.1 MB

    pre0_k<<<16, 256, 0, stream>>>(emb_w, emb_b, wq_w, wq_b, wv_w, wv_b, wo_w, wo_b,
                                   bufWp, bprime, bufWvo, bufbvo, Asum);
    qkv_k<<<516, 256, 0, stream>>>(PE, bufWp, bprime, PFX, wk_w, wk_b, CF, jc_w, jc_b,
                                   bufQ, bufK, bufC);
    flash6_k<<<dim3(21, NSPLIT, 8), 256, 0, stream>>>(bufQ, bufK, PFX, Opart, mpart, lpart);
    megatail_k<<<dim3(63, 8), 256, 0, stream>>>(Opart, mpart, lpart, bufWvo, bufbvo,
                                                jp_w, jp_b, bufC, CF, Asum, cpe);
    c12_k<<<128, 256, 0, stream>>>(cpe, Asum, c1_w, c1_b, c2_w, part2);
    c3m_k<<<8, 256, 0, stream>>>(part2, c2_b, c3_w, c3_b, c4_w, c4_b, (float*)d_out);
}

// Round 11
// 280.283 us; speedup vs baseline: 1.2057x; 1.2057x over previous
//
#include <hip/hip_runtime.h>
#include <hip/hip_bf16.h>
#include <math.h>

#define LP 1000
#define NCMP 64
#define NSPLIT 4

typedef _Float16 f16;
typedef f16   v8h __attribute__((ext_vector_type(8)));
typedef float v4f __attribute__((ext_vector_type(4)));

__device__ __forceinline__ float rcp_fast(float x) { return __builtin_amdgcn_rcpf(x); }
__device__ __forceinline__ void fsplit(float x, f16& h, f16& l) {
    h = (f16)x; l = (f16)(x - (float)h);
}

// ---------------- GEMM core: Y[M,128] = op(X)[M,K] @ W[K,128] + b ----------------
// 32-row tile, 256 threads, thread 4x4, X transposed in LDS, software-pipelined.
// Shared buffers passed in so kernels with multiple paths declare LDS once.
__device__ __forceinline__ void gemm_core(float (*Ws)[128], float (*Xt)[36],
                                          const float* X, const float* W, const float* bias,
                                          float* Y, int K, int rowbase, bool relu_in)
{
    const int t  = threadIdx.x;
    const int r0 = (t >> 5) * 4;
    const int c0 = (t & 31) * 4;
    const int xr = t >> 3, xk = (t & 7) << 2;
    const int xrow = rowbase + xr;
    float4 xv = *(const float4*)(X + (long)xrow * K + xk);
    float4 wv[4];
    #pragma unroll
    for (int u = 0; u < 4; ++u) {
        int s = t + u * 256, r = s >> 5, cb = (s & 31) << 2;
        wv[u] = *(const float4*)(W + (long)r * 128 + cb);
    }
    float acc[4][4] = {};
    for (int k0 = 0; k0 < K; k0 += 32) {
        float4 xs = xv;
        if (relu_in) { xs.x = fmaxf(xs.x,0.f); xs.y = fmaxf(xs.y,0.f);
                       xs.z = fmaxf(xs.z,0.f); xs.w = fmaxf(xs.w,0.f); }
        Xt[xk+0][xr] = xs.x; Xt[xk+1][xr] = xs.y; Xt[xk+2][xr] = xs.z; Xt[xk+3][xr] = xs.w;
        #pragma unroll
        for (int u = 0; u < 4; ++u) {
            int s = t + u * 256, r = s >> 5, cb = (s & 31) << 2;
            *(float4*)&Ws[r][cb] = wv[u];
        }
        __syncthreads();
        if (k0 + 32 < K) {
            xv = *(const float4*)(X + (long)xrow * K + k0 + 32 + xk);
            #pragma unroll
            for (int u = 0; u < 4; ++u) {
                int s = t + u * 256, r = s >> 5, cb = (s & 31) << 2;
                wv[u] = *(const float4*)(W + (long)(k0 + 32 + r) * 128 + cb);
            }
        }
        #pragma unroll
        for (int kk = 0; kk < 32; ++kk) {
            float4 w4 = *(const float4*)&Ws[kk][c0];
            float4 x4 = *(const float4*)&Xt[kk][r0];
            acc[0][0] = fmaf(x4.x, w4.x, acc[0][0]); acc[0][1] = fmaf(x4.x, w4.y, acc[0][1]);
            acc[0][2] = fmaf(x4.x, w4.z, acc[0][2]); acc[0][3] = fmaf(x4.x, w4.w, acc[0][3]);
            acc[1][0] = fmaf(x4.y, w4.x, acc[1][0]); acc[1][1] = fmaf(x4.y, w4.y, acc[1][1]);
            acc[1][2] = fmaf(x4.y, w4.z, acc[1][2]); acc[1][3] = fmaf(x4.y, w4.w, acc[1][3]);
            acc[2][0] = fmaf(x4.z, w4.x, acc[2][0]); acc[2][1] = fmaf(x4.z, w4.y, acc[2][1]);
            acc[2][2] = fmaf(x4.z, w4.z, acc[2][2]); acc[2][3] = fmaf(x4.z, w4.w, acc[2][3]);
            acc[3][0] = fmaf(x4.w, w4.x, acc[3][0]); acc[3][1] = fmaf(x4.w, w4.y, acc[3][1]);
            acc[3][2] = fmaf(x4.w, w4.z, acc[3][2]); acc[3][3] = fmaf(x4.w, w4.w, acc[3][3]);
        }
        __syncthreads();
    }
    float4 bv = bias ? *(const float4*)(bias + c0) : make_float4(0.f,0.f,0.f,0.f);
    #pragma unroll
    for (int i = 0; i < 4; ++i) {
        int row = rowbase + r0 + i;
        float4 o;
        o.x = acc[i][0] + bv.x; o.y = acc[i][1] + bv.y;
        o.z = acc[i][2] + bv.z; o.w = acc[i][3] + bv.w;
        *(float4*)(Y + (long)row * 128 + c0) = o;
    }
}

struct H4 { f16 a, b, c, d; };   // 8-byte fp16 quad

// Same GEMM but epilogue writes fp16 hi/lo split arrays laid out [8][1024][128].
__device__ __forceinline__ void gemm_core16(float (*Ws)[128], float (*Xt)[36],
                                            const float* X, const float* W, const float* bias,
                                            f16* Yhi, f16* Ylo, int K, int rowbase)
{
    const int t  = threadIdx.x;
    const int r0 = (t >> 5) * 4;
    const int c0 = (t & 31) * 4;
    const int xr = t >> 3, xk = (t & 7) << 2;
    const int xrow = rowbase + xr;
    float4 xv = *(const float4*)(X + (long)xrow * K + xk);
    float4 wv[4];
    #pragma unroll
    for (int u = 0; u < 4; ++u) {
        int s = t + u * 256, r = s >> 5, cb = (s & 31) << 2;
        wv[u] = *(const float4*)(W + (long)r * 128 + cb);
    }
    float acc[4][4] = {};
    for (int k0 = 0; k0 < K; k0 += 32) {
        Xt[xk+0][xr] = xv.x; Xt[xk+1][xr] = xv.y; Xt[xk+2][xr] = xv.z; Xt[xk+3][xr] = xv.w;
        #pragma unroll
        for (int u = 0; u < 4; ++u) {
            int s = t + u * 256, r = s >> 5, cb = (s & 31) << 2;
            *(float4*)&Ws[r][cb] = wv[u];
        }
        __syncthreads();
        if (k0 + 32 < K) {
            xv = *(const float4*)(X + (long)xrow * K + k0 + 32 + xk);
            #pragma unroll
            for (int u = 0; u < 4; ++u) {
                int s = t + u * 256, r = s >> 5, cb = (s & 31) << 2;
                wv[u] = *(const float4*)(W + (long)(k0 + 32 + r) * 128 + cb);
            }
        }
        #pragma unroll
        for (int kk = 0; kk < 32; ++kk) {
            float4 w4 = *(const float4*)&Ws[kk][c0];
            float4 x4 = *(const float4*)&Xt[kk][r0];
            acc[0][0] = fmaf(x4.x, w4.x, acc[0][0]); acc[0][1] = fmaf(x4.x, w4.y, acc[0][1]);
            acc[0][2] = fmaf(x4.x, w4.z, acc[0][2]); acc[0][3] = fmaf(x4.x, w4.w, acc[0][3]);
            acc[1][0] = fmaf(x4.y, w4.x, acc[1][0]); acc[1][1] = fmaf(x4.y, w4.y, acc[1][1]);
            acc[1][2] = fmaf(x4.y, w4.z, acc[1][2]); acc[1][3] = fmaf(x4.y, w4.w, acc[1][3]);
            acc[2][0] = fmaf(x4.z, w4.x, acc[2][0]); acc[2][1] = fmaf(x4.z, w4.y, acc[2][1]);
            acc[2][2] = fmaf(x4.z, w4.z, acc[2][2]); acc[2][3] = fmaf(x4.z, w4.w, acc[2][3]);
            acc[3][0] = fmaf(x4.w, w4.x, acc[3][0]); acc[3][1] = fmaf(x4.w, w4.y, acc[3][1]);
            acc[3][2] = fmaf(x4.w, w4.z, acc[3][2]); acc[3][3] = fmaf(x4.w, w4.w, acc[3][3]);
        }
        __syncthreads();
    }
    float4 bv = *(const float4*)(bias + c0);
    #pragma unroll
    for (int i = 0; i < 4; ++i) {
        int row = rowbase + r0 + i;
        int bb = row / 1000, rr = row - bb * 1000;
        long base = ((long)bb * 1024 + rr) * 128 + c0;
        float o0 = acc[i][0]+bv.x, o1 = acc[i][1]+bv.y, o2 = acc[i][2]+bv.z, o3 = acc[i][3]+bv.w;
        H4 h, l;
        fsplit(o0, h.a, l.a); fsplit(o1, h.b, l.b); fsplit(o2, h.c, l.c); fsplit(o3, h.d, l.d);
        *(H4*)(Yhi + base) = h;
        *(H4*)(Ylo + base) = l;
    }
}

// ---- pre0: 0-9: Wp=emb_w@wq_w; 10: bp + zero Asum/cpe; 11-14: Wvo=wv_w@wo_w; 15: bvo ----
__global__ __launch_bounds__(256) void pre0_k(const float* __restrict__ emb_w, const float* __restrict__ emb_b,
                                              const float* __restrict__ wq_w, const float* __restrict__ wq_b,
                                              const float* __restrict__ wv_w, const float* __restrict__ wv_b,
                                              const float* __restrict__ wo_w, const float* __restrict__ wo_b,
                                              float* __restrict__ Wp, float* __restrict__ bp,
                                              float* __restrict__ Wvo, float* __restrict__ bvo,
                                              float* __restrict__ zbase)
{
    __shared__ __align__(16) float Ws[32][128];
    __shared__ __align__(16) float Xt[32][36];
    const int bid = blockIdx.x;
    if (bid < 10) { gemm_core(Ws, Xt, emb_w, wq_w, nullptr, Wp, 128, bid * 32, false); return; }
    if (bid >= 11 && bid < 15) { gemm_core(Ws, Xt, wv_w, wo_w, nullptr, Wvo, 128, (bid - 11) * 32, false); return; }
    int t = threadIdx.x;
    if (bid == 10 && t >= 128) {
        for (int i = t - 128; i < 1032; i += 128) zbase[i] = 0.f;
        return;
    }
    if (t < 128) {
        const float* vb = (bid == 10) ? emb_b : wv_b;
        const float* Wm = (bid == 10) ? wq_w  : wo_w;
        const float* ab = (bid == 10) ? wq_b  : wo_b;
        float a0 = 0.f, a1 = 0.f, a2 = 0.f, a3 = 0.f;
        for (int k = 0; k < 128; k += 4) {
            a0 = fmaf(vb[k+0], Wm[(k+0)*128 + t], a0);
            a1 = fmaf(vb[k+1], Wm[(k+1)*128 + t], a1);
            a2 = fmaf(vb[k+2], Wm[(k+2)*128 + t], a2);
            a3 = fmaf(vb[k+3], Wm[(k+3)*128 + t], a3);
        }
        float* dst = (bid == 10) ? bp : bvo;
        dst[t] = (a0 + a1) + (a2 + a3) + ab[t];
    }
}

// ---- qkv: 0-249 Q(fp16 split, K=320); 250-499 K(fp16 split); 500-515 Cj; 516-765 V^T prep ----
__global__ __launch_bounds__(256) void qkv_k(const float* __restrict__ PE, const float* __restrict__ Wp,
                                             const float* __restrict__ bp, const float* __restrict__ PFX,
                                             const float* __restrict__ wk_w, const float* __restrict__ wk_b,
                                             const float* __restrict__ CF, const float* __restrict__ jc_w,
                                             const float* __restrict__ jc_b,
                                             f16* __restrict__ Qhi, f16* __restrict__ Qlo,
                                             f16* __restrict__ Khi, f16* __restrict__ Klo,
                                             f16* __restrict__ Vthi, f16* __restrict__ Vtlo,
                                             float* __restrict__ Cj)
{
    __shared__ __align__(16) float Ws[32][128];
    __shared__ __align__(16) float Xt[32][36];
    const int bid = blockIdx.x;
    if (bid < 250) { gemm_core16(Ws, Xt, PE, Wp, bp, Qhi, Qlo, 320, bid * 32); return; }
    if (bid < 500) { gemm_core16(Ws, Xt, PFX, wk_w, wk_b, Khi, Klo, 128, (bid - 250) * 32); return; }
    if (bid < 516) { gemm_core(Ws, Xt, CF, jc_w, jc_b, Cj, 128, (bid - 500) * 32, true); return; }
    // V^T prep: V = raw PFX; write Vthi/Vtlo[b][d][row] fp16 (transpose, no LDS)
    const int t = threadIdx.x;
    const int rowbase = (bid - 516) * 32;
    const int d = t >> 1, half = t & 1;
    #pragma unroll 4
    for (int i = 0; i < 16; ++i) {
        int row = rowbase + half * 16 + i;
        int bb = row / 1000, rr = row - bb * 1000;
        float v = PFX[(long)row * 128 + d];
        f16 h, l; fsplit(v, h, l);
        long o = ((long)bb * 128 + d) * 1024 + rr;
        Vthi[o] = h; Vtlo[o] = l;
    }
}

// ---------------- flash7: split-fp16 MFMA flash. TQ=64 (4 waves x 16-row band), TK=64 ----------
// grid (16, NSPLIT, 8) = 512 blocks, 256 threads, ~54.5 KB LDS -> 2 blocks/CU.
// QK^T and PV each as 3x mfma_f32_16x16x32_f16 (hi*hi + hi*lo + lo*hi) == fp32 accuracy.
// Q A-frags from global fp16 (no LDS). K staged hi/lo LDS; V reg-prefetched, overwrites K.
// P: C-layout -> per-wave LDS -> A-layout (intra-wave, barrier-free round trip).
__global__ __launch_bounds__(256) void flash7_k(const f16* __restrict__ Qhi, const f16* __restrict__ Qlo,
                                                const f16* __restrict__ Khi, const f16* __restrict__ Klo,
                                                const f16* __restrict__ Vthi, const f16* __restrict__ Vtlo,
                                                float* __restrict__ Opart,
                                                float* __restrict__ mpart, float* __restrict__ lpart)
{
    __shared__ __align__(16) f16 KVhi[9216];     // K: [64][136] (<=8704) ; V^T: [128][72] (9216)
    __shared__ __align__(16) f16 KVlo[9216];
    __shared__ __align__(16) f16 Pshi[4][16 * 72];
    __shared__ __align__(16) f16 Pslo[4][16 * 72];
    const int t    = threadIdx.x;
    const int wv   = t >> 6;         // wave 0..3 -> rows wv*16..wv*16+15
    const int lane = t & 63;
    const int quad = lane >> 4;      // 0..3
    const int l4   = lane & 15;
    const int qt = blockIdx.x, sp = blockIdx.y, b = blockIdx.z;
    const int q0 = qt * 64;
    const float SCALE = 0.08838834764831845f;    // 1/sqrt(128)
    const float L2E   = 1.4426950408889634f;

    // Q A-fragments (A[m=l4][k=quad*8+j]), rows clamped (invalid rows masked at store)
    int qrow = q0 + wv * 16 + l4; if (qrow >= LP) qrow = LP - 1;
    const long qbase = ((long)b * 1024 + qrow) * 128;
    v8h qh[4], ql[4];
    #pragma unroll
    for (int kt4 = 0; kt4 < 4; ++kt4) {
        qh[kt4] = *(const v8h*)(Qhi + qbase + kt4 * 32 + quad * 8);
        ql[kt4] = *(const v8h*)(Qlo + qbase + kt4 * 32 + quad * 8);
    }
    float m_i[4] = { -3.0e38f, -3.0e38f, -3.0e38f, -3.0e38f };
    float l_i[4] = { 0.f, 0.f, 0.f, 0.f };
    v4f  O[8];
    #pragma unroll
    for (int dt = 0; dt < 8; ++dt) O[dt] = (v4f){0.f, 0.f, 0.f, 0.f};

    for (int kt = sp * 4; kt < sp * 4 + 4; ++kt) {
        const int key0 = kt * 64;
        __syncthreads();                              // (A) prev PV done with KV buffers
        #pragma unroll
        for (int u = 0; u < 4; ++u) {                 // stage K hi/lo (64x128 fp16 each)
            int ch = t + u * 256;                     // 0..1023
            int r = ch >> 4, co = (ch & 15) * 8;
            long ga = ((long)b * 1024 + key0 + r) * 128 + co;
            *(v8h*)(KVhi + r * 136 + co) = *(const v8h*)(Khi + ga);
            *(v8h*)(KVlo + r * 136 + co) = *(const v8h*)(Klo + ga);
        }
        __syncthreads();                              // (B) K visible
        v8h vh[4], vl[4];
        #pragma unroll
        for (int u = 0; u < 4; ++u) {                 // V^T prefetch (in flight under QK)
            int ch = t + u * 256;
            int d = ch >> 3, co = (ch & 7) * 8;
            long ga = ((long)b * 128 + d) * 1024 + key0 + co;
            vh[u] = *(const v8h*)(Vthi + ga);
            vl[u] = *(const v8h*)(Vtlo + ga);
        }
        // ---- QK^T: S[16x64] per wave = 4 ntiles x 4 ktiles x 3 mfma ----
        v4f S[4];
        #pragma unroll
        for (int nt = 0; nt < 4; ++nt) S[nt] = (v4f){0.f, 0.f, 0.f, 0.f};
        #pragma unroll
        for (int nt = 0; nt < 4; ++nt) {
            const int rb = (nt * 16 + l4) * 136;
            #pragma unroll
            for (int kt4 = 0; kt4 < 4; ++kt4) {
                v8h bh = *(const v8h*)(KVhi + rb + kt4 * 32 + quad * 8);
                v8h bl = *(const v8h*)(KVlo + rb + kt4 * 32 + quad * 8);
                S[nt] = __builtin_amdgcn_mfma_f32_16x16x32_f16(qh[kt4], bh, S[nt], 0, 0, 0);
                S[nt] = __builtin_amdgcn_mfma_f32_16x16x32_f16(qh[kt4], bl, S[nt], 0, 0, 0);
                S[nt] = __builtin_amdgcn_mfma_f32_16x16x32_f16(ql[kt4], bh, S[nt], 0, 0, 0);
            }
        }
        // scale + key mask (C-layout: col = key0 + nt*16 + l4; row = quad*4 + r)
        #pragma unroll
        for (int nt = 0; nt < 4; ++nt) {
            bool valid = (key0 + nt * 16 + l4) < LP;
            #pragma unroll
            for (int r = 0; r < 4; ++r)
                S[nt][r] = valid ? S[nt][r] * SCALE : -3.0e38f;
        }
        // online softmax: per reg r, reduce over nt + 16-lane shuffles
        float alpha[4];
        #pragma unroll
        for (int r = 0; r < 4; ++r) {
            float tm = fmaxf(fmaxf(S[0][r], S[1][r]), fmaxf(S[2][r], S[3][r]));
            tm = fmaxf(tm, __shfl_xor(tm, 1));
            tm = fmaxf(tm, __shfl_xor(tm, 2));
            tm = fmaxf(tm, __shfl_xor(tm, 4));
            tm = fmaxf(tm, __shfl_xor(tm, 8));
            float mnew = fmaxf(m_i[r], tm);
            alpha[r] = exp2f((m_i[r] - mnew) * L2E);
            float ps = 0.f;
            #pragma unroll
            for (int nt = 0; nt < 4; ++nt) {
                float p = exp2f((S[nt][r] - mnew) * L2E);
                S[nt][r] = p;
                ps += p;
            }
            ps += __shfl_xor(ps, 1);
            ps += __shfl_xor(ps, 2);
            ps += __shfl_xor(ps, 4);
            ps += __shfl_xor(ps, 8);
            l_i[r] = l_i[r] * alpha[r] + ps;
            m_i[r] = mnew;
        }
        #pragma unroll
        for (int dt = 0; dt < 8; ++dt) {
            O[dt][0] *= alpha[0]; O[dt][1] *= alpha[1];
            O[dt][2] *= alpha[2]; O[dt][3] *= alpha[3];
        }
        __syncthreads();                              // (C) QK reads of KV done
        #pragma unroll
        for (int u = 0; u < 4; ++u) {                 // V regs -> LDS (overwrite K)
            int ch = t + u * 256;
            int d = ch >> 3, co = (ch & 7) * 8;
            *(v8h*)(KVhi + d * 72 + co) = vh[u];
            *(v8h*)(KVlo + d * 72 + co) = vl[u];
        }
        // P: C-layout -> per-wave LDS (fp16 hi/lo); intra-wave round trip
        #pragma unroll
        for (int nt = 0; nt < 4; ++nt) {
            int col = nt * 16 + l4;
            #pragma unroll
            for (int r = 0; r < 4; ++r) {
                f16 ph, pl; fsplit(S[nt][r], ph, pl);
                Pshi[wv][(quad * 4 + r) * 72 + col] = ph;
                Pslo[wv][(quad * 4 + r) * 72 + col] = pl;
            }
        }
        __syncthreads();                              // (D) V visible
        // ---- PV: O[16x128] per wave = 8 dtiles x 2 ktiles x 3 mfma ----
        #pragma unroll
        for (int kc = 0; kc < 2; ++kc) {
            v8h pah = *(const v8h*)(Pshi[wv] + l4 * 72 + kc * 32 + quad * 8);
            v8h pal = *(const v8h*)(Pslo[wv] + l4 * 72 + kc * 32 + quad * 8);
            #pragma unroll
            for (int dt = 0; dt < 8; ++dt) {
                v8h vfh = *(const v8h*)(KVhi + (dt * 16 + l4) * 72 + kc * 32 + quad * 8);
                v8h vfl = *(const v8h*)(KVlo + (dt * 16 + l4) * 72 + kc * 32 + quad * 8);
                O[dt] = __builtin_amdgcn_mfma_f32_16x16x32_f16(pah, vfh, O[dt], 0, 0, 0);
                O[dt] = __builtin_amdgcn_mfma_f32_16x16x32_f16(pah, vfl, O[dt], 0, 0, 0);
                O[dt] = __builtin_amdgcn_mfma_f32_16x16x32_f16(pal, vfh, O[dt], 0, 0, 0);
            }
        }
    }
    // epilogue: C-layout scatter (row = q0 + wv*16 + quad*4 + r, col = dt*16 + l4)
    #pragma unroll
    for (int r = 0; r < 4; ++r) {
        int row = q0 + wv * 16 + quad * 4 + r;
        if (row < LP) {
            long base = (long)sp * 1024000 + ((long)b * LP + row) * 128;
            #pragma unroll
            for (int dt = 0; dt < 8; ++dt)
                Opart[base + dt * 16 + l4] = O[dt][r];
            if (l4 == 0) {
                mpart[(long)sp * 8000 + b * LP + row] = m_i[r];
                lpart[(long)sp * 8000 + b * LP + row] = l_i[r];
            }
        }
    }
}

// ---------------- megatail: per 16-row tile, wo+jp+sigA+tanh-reduce fused (NSPLIT merge) --------
__global__ __launch_bounds__(256) void megatail_k(
    const float* __restrict__ Opart, const float* __restrict__ mp, const float* __restrict__ lp,
    const float* __restrict__ Wvo, const float* __restrict__ bvo,
    const float* __restrict__ jp_w, const float* __restrict__ jp_b,
    const float* __restrict__ Cj, const float* __restrict__ CF,
    float* __restrict__ Asum, float* __restrict__ cpe)
{
    __shared__ __align__(16) float WsA[32][132];
    __shared__ __align__(16) float Xt[32][20];
    __shared__ __align__(16) float AttS[16][132];
    __shared__ __align__(16) float Csh[64][132];
    __shared__ __align__(16) float Ash[16][64];
    __shared__ __align__(16) float AshT[64][20];
    __shared__ float red[256];
    const int t = threadIdx.x;
    const int p0 = blockIdx.x * 16;
    const int b  = blockIdx.y;
    const float L2E = 1.4426950408889634f;

    #pragma unroll
    for (int u = 0; u < 8; ++u) {
        int s = t + u * 256, r = s >> 5, cb = (s & 31) << 2;
        *(float4*)&Csh[r][cb] = *(const float4*)(Cj + ((long)b * NCMP + r) * 128 + cb);
    }
    const int r0 = (t >> 5) * 2, c0 = (t & 31) * 4;
    const int xr = t >> 3, xk = (t & 7) << 2;
    int prow = p0 + xr; if (prow > LP - 1) prow = LP - 1;
    const long g = (long)b * LP + prow;
    float wgt[NSPLIT]; float linv = 0.f;
    if (t < 128) {
        float mm = -3.0e38f;
        #pragma unroll
        for (int s = 0; s < NSPLIT; ++s) mm = fmaxf(mm, mp[g + (long)s * 8000]);
        float ls = 0.f;
        #pragma unroll
        for (int s = 0; s < NSPLIT; ++s) {
            wgt[s] = exp2f((mp[g + (long)s * 8000] - mm) * L2E);
            ls += wgt[s] * lp[g + (long)s * 8000];
        }
        linv = 1.0f / ls;
    }
    float4 xv = make_float4(0.f,0.f,0.f,0.f);
    float4 wv[4];
    if (t < 128) {
        float4 a = make_float4(0.f,0.f,0.f,0.f);
        #pragma unroll
        for (int s = 0; s < NSPLIT; ++s) {
            float4 p = *(const float4*)(Opart + (long)s * 1024000 + g * 128 + xk);
            a.x = fmaf(wgt[s], p.x, a.x); a.y = fmaf(wgt[s], p.y, a.y);
            a.z = fmaf(wgt[s], p.z, a.z); a.w = fmaf(wgt[s], p.w, a.w);
        }
        xv = make_float4(a.x * linv, a.y * linv, a.z * linv, a.w * linv);
    }
    #pragma unroll
    for (int u = 0; u < 4; ++u) {
        int s = t + u * 256, r = s >> 5, cb = (s & 31) << 2;
        wv[u] = *(const float4*)(Wvo + (long)r * 128 + cb);
    }
    float acc[2][4] = {};
    for (int k0 = 0; k0 < 128; k0 += 32) {
        if (t < 128) { Xt[xk+0][xr]=xv.x; Xt[xk+1][xr]=xv.y; Xt[xk+2][xr]=xv.z; Xt[xk+3][xr]=xv.w; }
        #pragma unroll
        for (int u = 0; u < 4; ++u) {
            int s = t + u * 256, r = s >> 5, cb = (s & 31) << 2;
            *(float4*)&WsA[r][cb] = wv[u];
        }
        __syncthreads();
        if (k0 + 32 < 128) {
            int kn = k0 + 32;
            if (t < 128) {
                float4 a = make_float4(0.f,0.f,0.f,0.f);
                #pragma unroll
                for (int s = 0; s < NSPLIT; ++s) {
                    float4 p = *(const float4*)(Opart + (long)s * 1024000 + g * 128 + kn + xk);
                    a.x = fmaf(wgt[s], p.x, a.x); a.y = fmaf(wgt[s], p.y, a.y);
                    a.z = fmaf(wgt[s], p.z, a.z); a.w = fmaf(wgt[s], p.w, a.w);
                }
                xv = make_float4(a.x * linv, a.y * linv, a.z * linv, a.w * linv);
            }
            #pragma unroll
            for (int u = 0; u < 4; ++u) {
                int s = t + u * 256, r = s >> 5, cb = (s & 31) << 2;
                wv[u] = *(const float4*)(Wvo + (long)(kn + r) * 128 + cb);
            }
        }
        #pragma unroll
        for (int kk = 0; kk < 32; ++kk) {
            float2 x2 = *(const float2*)&Xt[kk][r0];
            float4 w4 = *(const float4*)&WsA[kk][c0];
            acc[0][0]=fmaf(x2.x,w4.x,acc[0][0]); acc[0][1]=fmaf(x2.x,w4.y,acc[0][1]);
            acc[0][2]=fmaf(x2.x,w4.z,acc[0][2]); acc[0][3]=fmaf(x2.x,w4.w,acc[0][3]);
            acc[1][0]=fmaf(x2.y,w4.x,acc[1][0]); acc[1][1]=fmaf(x2.y,w4.y,acc[1][1]);
            acc[1][2]=fmaf(x2.y,w4.z,acc[1][2]); acc[1][3]=fmaf(x2.y,w4.w,acc[1][3]);
        }
        __syncthreads();
    }
    {
        float4 bv1 = *(const float4*)(bvo + c0);
        #pragma unroll
        for (int i = 0; i < 2; ++i)
            *(float4*)&AttS[r0 + i][c0] =
                make_float4(acc[i][0]+bv1.x, acc[i][1]+bv1.y, acc[i][2]+bv1.z, acc[i][3]+bv1.w);
    }
    float4 wv2[4];
    #pragma unroll
    for (int u = 0; u < 4; ++u) {
        int s = t + u * 256, r = s >> 5, cb = (s & 31) << 2;
        wv2[u] = *(const float4*)(jp_w + (long)r * 128 + cb);
    }
    float ac2[2][4] = {};
    for (int k0 = 0; k0 < 128; k0 += 32) {
        #pragma unroll
        for (int u = 0; u < 4; ++u) {
            int s = t + u * 256, r = s >> 5, cb = (s & 31) << 2;
            *(float4*)&WsA[r][cb] = wv2[u];
        }
        __syncthreads();
        if (k0 + 32 < 128) {
            #pragma unroll
            for (int u = 0; u < 4; ++u) {
                int s = t + u * 256, r = s >> 5, cb = (s & 31) << 2;
                wv2[u] = *(const float4*)(jp_w + (long)(k0 + 32 + r) * 128 + cb);
            }
        }
        #pragma unroll
        for (int kq = 0; kq < 8; ++kq) {
            float4 xa = *(const float4*)&AttS[r0 + 0][k0 + (kq << 2)];
            float4 xb = *(const float4*)&AttS[r0 + 1][k0 + (kq << 2)];
            #pragma unroll
            for (int e = 0; e < 4; ++e) {
                float x0 = fmaxf((e==0)?xa.x:(e==1)?xa.y:(e==2)?xa.z:xa.w, 0.f);
                float x1 = fmaxf((e==0)?xb.x:(e==1)?xb.y:(e==2)?xb.z:xb.w, 0.f);
                float4 w4 = *(const float4*)&WsA[(kq << 2) + e][c0];
                ac2[0][0]=fmaf(x0,w4.x,ac2[0][0]); ac2[0][1]=fmaf(x0,w4.y,ac2[0][1]);
                ac2[0][2]=fmaf(x0,w4.z,ac2[0][2]); ac2[0][3]=fmaf(x0,w4.w,ac2[0][3]);
                ac2[1][0]=fmaf(x1,w4.x,ac2[1][0]); ac2[1][1]=fmaf(x1,w4.y,ac2[1][1]);
                ac2[1][2]=fmaf(x1,w4.z,ac2[1][2]); ac2[1][3]=fmaf(x1,w4.w,ac2[1][3]);
            }
        }
        __syncthreads();
    }
    float (*Psh)[132] = WsA;
    {
        float4 b2 = *(const float4*)(jp_b + c0);
        #pragma unroll
        for (int i = 0; i < 2; ++i)
            *(float4*)&Psh[r0 + i][c0] =
                make_float4(ac2[i][0]+b2.x, ac2[i][1]+b2.y, ac2[i][2]+b2.z, ac2[i][3]+b2.w);
    }
    __syncthreads();
    const int tr = t >> 4, tc = t & 15;
    float sacc[4] = {};
    #pragma unroll 4
    for (int d4 = 0; d4 < 32; ++d4) {
        float4 p4 = *(const float4*)&Psh[tr][d4 << 2];
        #pragma unroll
        for (int j = 0; j < 4; ++j) {
            float4 cv = *(const float4*)&Csh[tc + (j << 4)][d4 << 2];
            sacc[j] += p4.x*cv.x + p4.y*cv.y + p4.z*cv.z + p4.w*cv.w;
        }
    }
    float lsum = 0.f;
    {
        int gi = p0 + tr;
        #pragma unroll
        for (int j = 0; j < 4; ++j) {
            float sg = rcp_fast(1.f + exp2f(-sacc[j] * L2E));
            if (gi < LP) {
                Ash[tr][tc + (j << 4)]  = sg;
                AshT[tc + (j << 4)][tr] = sg;
                lsum += sg;
            }
        }
    }
    red[t] = lsum;
    __syncthreads();
    for (int off = 128; off > 0; off >>= 1) {
        if (t < off) red[t] += red[t + off];
        __syncthreads();
    }
    if (t == 0) atomicAdd(Asum + b, red[0]);
    __syncthreads();
    #pragma unroll
    for (int u = 0; u < 8; ++u) {
        int s = t + u * 256, r = s >> 5, cb = (s & 31) << 2;
        *(float4*)&Csh[r][cb] = *(const float4*)(CF + ((long)b * NCMP + r) * 128 + cb);
    }
    __syncthreads();
    const float TWO_L2E = 2.8853900817779268f;
    const int d  = t & 127;
    const int kh = t >> 7;
    const int iiN = (LP - p0 < 16) ? (LP - p0) : 16;
    float areg[16];
    #pragma unroll
    for (int ii = 0; ii < 16; ++ii) areg[ii] = AttS[ii][d] * TWO_L2E;
    float accD = 0.f;
    for (int kk = 0; kk < 32; ++kk) {
        const int k = (kh << 5) + kk;
        const float cv = Csh[k][d];
        for (int iq = 0; iq < iiN; iq += 4) {
            float4 a4 = *(const float4*)&AshT[k][iq];
            float e0 = exp2f(areg[iq+0] * cv);
            float e1 = exp2f(areg[iq+1] * cv);
            float e2 = exp2f(areg[iq+2] * cv);
            float e3 = exp2f(areg[iq+3] * cv);
            accD = fmaf(1.f - 2.f * rcp_fast(e0 + 1.f), a4.x, accD);
            accD = fmaf(1.f - 2.f * rcp_fast(e1 + 1.f), a4.y, accD);
            accD = fmaf(1.f - 2.f * rcp_fast(e2 + 1.f), a4.z, accD);
            accD = fmaf(1.f - 2.f * rcp_fast(e3 + 1.f), a4.w, accD);
        }
    }
    red[t] = accD;
    __syncthreads();
    if (t < 128) atomicAdd(cpe + (long)b * 128 + t, red[t] + red[t + 128]);
}

// ---------------- c12: fused c1 slice + c2 split-K partials, 128 blocks ----------------
__global__ __launch_bounds__(256) void c12_k(const float* __restrict__ cpe, const float* __restrict__ Asum,
                                             const float* __restrict__ c1_w, const float* __restrict__ c1_b,
                                             const float* __restrict__ c2_w, float* __restrict__ part)
{
    __shared__ float sc[8][128];
    __shared__ float ins[8][8];
    const int t = threadIdx.x, ks = blockIdx.x, k0 = ks * 8;
    #pragma unroll
    for (int u = 0; u < 4; ++u) {
        int idx = t + u * 256;
        sc[idx >> 7][idx & 127] = cpe[idx] * rcp_fast(Asum[idx >> 7]);
    }
    __syncthreads();
    if (t < 64) {
        int b = t >> 3, kk = t & 7;
        int n1 = k0 + kk;
        float a0 = 0.f, a1 = 0.f, a2 = 0.f, a3 = 0.f;
        #pragma unroll 8
        for (int j = 0; j < 128; j += 4) {
            a0 = fmaf(sc[b][j+0], c1_w[(long)(j+0)*1024 + n1], a0);
            a1 = fmaf(sc[b][j+1], c1_w[(long)(j+1)*1024 + n1], a1);
            a2 = fmaf(sc[b][j+2], c1_w[(long)(j+2)*1024 + n1], a2);
            a3 = fmaf(sc[b][j+3], c1_w[(long)(j+3)*1024 + n1], a3);
        }
        ins[b][kk] = fmaxf((a0 + a1) + (a2 + a3) + c1_b[n1], 0.f);
    }
    __syncthreads();
    const int n = (t & 63) * 4 + (t >> 6) * 256;
    float4 acc[8] = {};
    #pragma unroll
    for (int kk = 0; kk < 8; ++kk) {
        float4 w4 = *(const float4*)(c2_w + (long)(k0 + kk) * 1024 + n);
        #pragma unroll
        for (int b = 0; b < 8; ++b) {
            float s = ins[b][kk];
            acc[b].x = fmaf(s, w4.x, acc[b].x); acc[b].y = fmaf(s, w4.y, acc[b].y);
            acc[b].z = fmaf(s, w4.z, acc[b].z); acc[b].w = fmaf(s, w4.w, acc[b].w);
        }
    }
    #pragma unroll
    for (int b = 0; b < 8; ++b)
        *(float4*)(part + ((long)(ks * 8 + b)) * 1024 + n) = acc[b];
}

// ------- c3+c4 fused -------
__global__ __launch_bounds__(256) void c3m_k(const float* __restrict__ part2, const float* __restrict__ c2_b,
                                             const float* __restrict__ c3_w, const float* __restrict__ c3_b,
                                             const float* __restrict__ c4_w, const float* __restrict__ c4_b,
                                             float* __restrict__ out)
{
    __shared__ float Hs[1024];
    __shared__ float red[256];
    const int t = threadIdx.x, b = blockIdx.x;
    float4 acc4 = make_float4(0.f,0.f,0.f,0.f);
    #pragma unroll 4
    for (int ks = 0; ks < 128; ++ks) {
        float4 p = *(const float4*)(part2 + ((long)(ks * 8 + b)) * 1024 + t * 4);
        acc4.x += p.x; acc4.y += p.y; acc4.z += p.z; acc4.w += p.w;
    }
    {
        float4 bb = *(const float4*)(c2_b + t * 4);
        Hs[t*4+0] = fmaxf(acc4.x + bb.x, 0.f);
        Hs[t*4+1] = fmaxf(acc4.y + bb.y, 0.f);
        Hs[t*4+2] = fmaxf(acc4.z + bb.z, 0.f);
        Hs[t*4+3] = fmaxf(acc4.w + bb.w, 0.f);
    }
    __syncthreads();
    float a0 = 0.f, a1 = 0.f, a2 = 0.f, a3 = 0.f;
    #pragma unroll 8
    for (int k = 0; k < 1024; k += 4) {
        a0 = fmaf(Hs[k+0], c3_w[(long)(k+0)*256 + t], a0);
        a1 = fmaf(Hs[k+1], c3_w[(long)(k+1)*256 + t], a1);
        a2 = fmaf(Hs[k+2], c3_w[(long)(k+2)*256 + t], a2);
        a3 = fmaf(Hs[k+3], c3_w[(long)(k+3)*256 + t], a3);
    }
    float h3v = fmaxf((a0 + a1) + (a2 + a3) + c3_b[t], 0.f);
    red[t] = h3v * c4_w[t];
    __syncthreads();
    for (int off = 128; off > 0; off >>= 1) {
        if (t < off) red[t] += red[t + off];
        __syncthreads();
    }
    if (t == 0) out[b] = red[0] + c4_b[0];
}

extern "C" void kernel_launch(void* const* d_in, const int* in_sizes, int n_in,
                              void* d_out, int out_size, void* d_ws, size_t ws_size,
                              hipStream_t stream)
{
    const float* PE   = (const float*)d_in[0];
    const float* PFX  = (const float*)d_in[1];
    const float* CF   = (const float*)d_in[2];
    const float* emb_w = (const float*)d_in[3];  const float* emb_b = (const float*)d_in[4];
    const float* wq_w  = (const float*)d_in[5];  const float* wq_b  = (const float*)d_in[6];
    const float* wk_w  = (const float*)d_in[7];  const float* wk_b  = (const float*)d_in[8];
    const float* wv_w  = (const float*)d_in[9];  const float* wv_b  = (const float*)d_in[10];
    const float* wo_w  = (const float*)d_in[11]; const float* wo_b  = (const float*)d_in[12];
    const float* jp_w  = (const float*)d_in[13]; const float* jp_b  = (const float*)d_in[14];
    const float* jc_w  = (const float*)d_in[15]; const float* jc_b  = (const float*)d_in[16];
    const float* c1_w  = (const float*)d_in[17]; const float* c1_b  = (const float*)d_in[18];
    const float* c2_w  = (const float*)d_in[19]; const float* c2_b  = (const float*)d_in[20];
    const float* c3_w  = (const float*)d_in[21]; const float* c3_b  = (const float*)d_in[22];
    const float* c4_w  = (const float*)d_in[23]; const float* c4_b  = (const float*)d_in[24];

    float* ws     = (float*)d_ws;
    f16*  Qhi   = (f16*)ws;                        // 8*1024*128 fp16 = 524,288 float-slots
    f16*  Qlo   = (f16*)(ws + 524288);
    f16*  Khi   = (f16*)(ws + 1048576);
    f16*  Klo   = (f16*)(ws + 1572864);
    f16*  Vthi  = (f16*)(ws + 2097152);            // [8][128][1024] fp16
    f16*  Vtlo  = (f16*)(ws + 2621440);
    float* bufC   = ws + 3145728;                  //    65,536 (jc output)
    float* Opart  = bufC + 65536;                  // 4,096,000 (4-way flash partials)
    float* mpart  = Opart + 4096000;               //    32,000
    float* lpart  = mpart + 32000;                 //    32,000
    float* Asum   = lpart + 32000;                 //         8
    float* cpe    = Asum + 8;                      //     1,024 (zeroed with Asum in pre0)
    float* bprime = cpe + 1024;                    //       128
    float* bufWp  = bprime + 128;                  //    40,960 (emb_w @ wq_w)
    float* bufWvo = bufWp + 40960;                 //    16,384 (wv_w @ wo_w)
    float* bufbvo = bufWvo + 16384;                //       128
    float* part2  = ws;                            // c2 partials (1,048,576) alias Q/K fp16 region
    // total ~7.44M floats = ~29.8 MB

    pre0_k<<<16, 256, 0, stream>>>(emb_w, emb_b, wq_w, wq_b, wv_w, wv_b, wo_w, wo_b,
                                   bufWp, bprime, bufWvo, bufbvo, Asum);
    qkv_k<<<766, 256, 0, stream>>>(PE, bufWp, bprime, PFX, wk_w, wk_b, CF, jc_w, jc_b,
                                   Qhi, Qlo, Khi, Klo, Vthi, Vtlo, bufC);
    flash7_k<<<dim3(16, NSPLIT, 8), 256, 0, stream>>>(Qhi, Qlo, Khi, Klo, Vthi, Vtlo,
                                                      Opart, mpart, lpart);
    megatail_k<<<dim3(63, 8), 256, 0, stream>>>(Opart, mpart, lpart, bufWvo, bufbvo,
                                                jp_w, jp_b, bufC, CF, Asum, cpe);
    c12_k<<<128, 256, 0, stream>>>(cpe, Asum, c1_w, c1_b, c2_w, part2);
    c3m_k<<<8, 256, 0, stream>>>(part2, c2_b, c3_w, c3_b, c4_w, c4_b, (float*)d_out);
}